// Round 1
// baseline (1751.052 us; speedup 1.0000x reference)
//
#include <hip/hip_runtime.h>

#define NN 50000
#define NE 800000
#define NG 128
#define NF 64
#define EPSV 1e-5f

// ======================= CSR build =======================
__global__ void k_count(const int* __restrict__ dst, int* __restrict__ cnt) {
  int e = blockIdx.x * 256 + threadIdx.x;
  if (e < NE) atomicAdd(&cnt[dst[e]], 1);
}

__global__ __launch_bounds__(1024) void k_scan(const int* __restrict__ cnt,
                                               int* __restrict__ off,
                                               int* __restrict__ cursor) {
  __shared__ int sh[1024];
  int tid = threadIdx.x;
  const int CH = (NN + 1023) / 1024;  // 49
  int b = tid * CH;
  int e = b + CH; if (e > NN) e = NN;
  if (b > NN) b = NN;
  int sum = 0;
  for (int i = b; i < e; ++i) sum += cnt[i];
  sh[tid] = sum;
  __syncthreads();
  // inclusive scan over 1024 partials (Hillis-Steele)
  for (int d = 1; d < 1024; d <<= 1) {
    int t = (tid >= d) ? sh[tid - d] : 0;
    __syncthreads();
    sh[tid] += t;
    __syncthreads();
  }
  int excl = sh[tid] - sum;
  for (int i = b; i < e; ++i) { off[i] = excl; cursor[i] = excl; excl += cnt[i]; }
  if (tid == 1023) off[NN] = sh[1023];
}

__global__ void k_fill(const int* __restrict__ src, const int* __restrict__ dst,
                       int* __restrict__ cursor, int* __restrict__ csr) {
  int e = blockIdx.x * 256 + threadIdx.x;
  if (e < NE) {
    int p = atomicAdd(&cursor[dst[e]], 1);
    csr[p] = src[e];
  }
}

__global__ void k_gcount(const int* __restrict__ batch, int* __restrict__ gcnt) {
  int i = blockIdx.x * 256 + threadIdx.x;
  if (i < NN) atomicAdd(&gcnt[batch[i]], 1);
}

// ============ mean aggregation: one wave per node, lane = feature ============
__global__ __launch_bounds__(256) void k_agg(const float* __restrict__ in,
                                             const int* __restrict__ off,
                                             const int* __restrict__ csr,
                                             float* __restrict__ out) {
  int wid = (blockIdx.x * 256 + threadIdx.x) >> 6;
  int lane = threadIdx.x & 63;
  if (wid >= NN) return;
  int s0 = off[wid], s1 = off[wid + 1];
  float acc = 0.f;
  for (int j = s0; j < s1; ++j) {
    int s = csr[j];
    acc += in[s * NF + lane];
  }
  int d = s1 - s0;
  out[wid * NF + lane] = (d > 0) ? acc / (float)d : 0.f;
}

// ============ dual GEMM: out = A@Wl + bl + X@Wr  (wave computes 64 cols/row) ============
__global__ __launch_bounds__(256) void k_sage_linear(const float* __restrict__ A,
                                                     const float* __restrict__ X,
                                                     const float* __restrict__ Wl,
                                                     const float* __restrict__ bl,
                                                     const float* __restrict__ Wr,
                                                     float* __restrict__ out) {
  __shared__ float sWl[64][64];
  __shared__ float sWr[64][64];
  int tid = threadIdx.x;
  for (int i = tid; i < 64 * 64; i += 256) {
    sWl[i >> 6][i & 63] = Wl[i];
    sWr[i >> 6][i & 63] = Wr[i];
  }
  __syncthreads();
  int lane = tid & 63;
  int wave = tid >> 6;
  const int RPW = 8;                       // rows per wave
  int row0 = blockIdx.x * (4 * RPW) + wave * RPW;
  float bias = bl[lane];
  for (int r = row0; r < row0 + RPW; ++r) {
    if (r >= NN) break;
    float av = A[r * NF + lane];
    float xv = X[r * NF + lane];
    float acc = bias;
#pragma unroll
    for (int k = 0; k < 64; ++k) {
      acc += __shfl(av, k) * sWl[k][lane];
      acc += __shfl(xv, k) * sWr[k][lane];
    }
    out[r * NF + lane] = acc;
  }
}

// ============ skip GEMM: out = add0 (+ add1) + X@W ============
__global__ __launch_bounds__(256) void k_skip_linear(const float* __restrict__ X,
                                                     const float* __restrict__ W,
                                                     const float* __restrict__ add0,
                                                     const float* __restrict__ add1,
                                                     float* __restrict__ out) {
  __shared__ float sW[64][64];
  int tid = threadIdx.x;
  for (int i = tid; i < 64 * 64; i += 256) sW[i >> 6][i & 63] = W[i];
  __syncthreads();
  int lane = tid & 63;
  int wave = tid >> 6;
  const int RPW = 8;
  int row0 = blockIdx.x * (4 * RPW) + wave * RPW;
  for (int r = row0; r < row0 + RPW; ++r) {
    if (r >= NN) break;
    float xv = X[r * NF + lane];
    float acc = add0[r * NF + lane];
    if (add1) acc += add1[r * NF + lane];
#pragma unroll
    for (int k = 0; k < 64; ++k) {
      acc += __shfl(xv, k) * sW[k][lane];
    }
    out[r * NF + lane] = acc;
  }
}

// ============ graph LayerNorm stats: wave per node ============
__global__ __launch_bounds__(256) void k_ln_stats(const float* __restrict__ t,
                                                  const int* __restrict__ batch,
                                                  float* __restrict__ gsum,
                                                  float* __restrict__ gsq) {
  int wid = (blockIdx.x * 256 + threadIdx.x) >> 6;
  int lane = threadIdx.x & 63;
  if (wid >= NN) return;
  float v = t[wid * NF + lane];
  float s = v, s2 = v * v;
#pragma unroll
  for (int d = 32; d > 0; d >>= 1) {
    s += __shfl_xor(s, d);
    s2 += __shfl_xor(s2, d);
  }
  if (lane == 0) {
    int g = batch[wid];
    atomicAdd(&gsum[g], s);
    atomicAdd(&gsq[g], s2);
  }
}

// ============ graph LayerNorm apply + affine + PReLU (in-place capable) ============
__global__ __launch_bounds__(256) void k_ln_apply(const float* __restrict__ t,
                                                  const int* __restrict__ batch,
                                                  const int* __restrict__ gcnt,
                                                  const float* __restrict__ gsum,
                                                  const float* __restrict__ gsq,
                                                  const float* __restrict__ w,
                                                  const float* __restrict__ b,
                                                  const float* __restrict__ alpha,
                                                  float* __restrict__ out) {
  int wid = (blockIdx.x * 256 + threadIdx.x) >> 6;
  int lane = threadIdx.x & 63;
  if (wid >= NN) return;
  int g = batch[wid];
  float norm = fmaxf((float)gcnt[g], 1.f) * (float)NF;
  float mean = gsum[g] / norm;
  float var = gsq[g] / norm - mean * mean;
  float rstd = rsqrtf(var + EPSV);
  float a = alpha[0];
  float v = t[wid * NF + lane];
  v = (v - mean) * rstd;
  v = v * w[lane] + b[lane];
  out[wid * NF + lane] = (v >= 0.f) ? v : a * v;
}

// ======================= launch =======================
extern "C" void kernel_launch(void* const* d_in, const int* in_sizes, int n_in,
                              void* d_out, int out_size, void* d_ws, size_t ws_size,
                              hipStream_t stream) {
  const float* x     = (const float*)d_in[0];
  const float* c0_Wl = (const float*)d_in[1];
  const float* c0_bl = (const float*)d_in[2];
  const float* c0_Wr = (const float*)d_in[3];
  const float* c1_Wl = (const float*)d_in[4];
  const float* c1_bl = (const float*)d_in[5];
  const float* c1_Wr = (const float*)d_in[6];
  const float* c2_Wl = (const float*)d_in[7];
  const float* c2_bl = (const float*)d_in[8];
  const float* c2_Wr = (const float*)d_in[9];
  const float* s0_W  = (const float*)d_in[10];
  const float* s1_W  = (const float*)d_in[11];
  const float* ln0_w = (const float*)d_in[12];
  const float* ln0_b = (const float*)d_in[13];
  const float* ln1_w = (const float*)d_in[14];
  const float* ln1_b = (const float*)d_in[15];
  const float* ln2_w = (const float*)d_in[16];
  const float* ln2_b = (const float*)d_in[17];
  const float* p0_a  = (const float*)d_in[18];
  const float* p1_a  = (const float*)d_in[19];
  const float* p2_a  = (const float*)d_in[20];
  const int*   ei    = (const int*)d_in[21];   // [2, E] int32
  const int*   batch = (const int*)d_in[22];   // [N] int32
  float* out = (float*)d_out;

  const int* src = ei;
  const int* dst = ei + NE;

  // ---- workspace layout (256B aligned) ----
  char* ws = (char*)d_ws;
  const size_t off_cnt    = 0;                          // N ints (zeroed)
  const size_t off_gcnt   = 200192;                     // G ints (zeroed)
  const size_t off_stats  = 200704;                     // 6*G floats (zeroed)
  const size_t zero_bytes = 203776;
  const size_t off_off    = 203776;                     // N+1 ints
  const size_t off_cursor = 404224;                     // N ints
  const size_t off_csr    = 604416;                     // E ints
  const size_t off_B1     = 3804416;                    // N*F floats
  const size_t off_B2     = off_B1 + 12800000;
  const size_t off_B3     = off_B2 + 12800000;
  const size_t off_B4     = off_B3 + 12800000;

  int*   cnt    = (int*)(ws + off_cnt);
  int*   gcnt   = (int*)(ws + off_gcnt);
  float* stats  = (float*)(ws + off_stats);
  int*   offp   = (int*)(ws + off_off);
  int*   cursor = (int*)(ws + off_cursor);
  int*   csr    = (int*)(ws + off_csr);
  float* B1     = (float*)(ws + off_B1);   // aggregation output
  float* B2     = (float*)(ws + off_B2);   // h1
  float* B3     = (float*)(ws + off_B3);   // z
  float* B4     = (float*)(ws + off_B4);   // h2
  (void)ws_size; (void)in_sizes; (void)n_in; (void)out_size;

  float* gsum0 = stats + 0 * NG; float* gsq0 = stats + 1 * NG;
  float* gsum1 = stats + 2 * NG; float* gsq1 = stats + 3 * NG;
  float* gsum2 = stats + 4 * NG; float* gsq2 = stats + 5 * NG;

  hipMemsetAsync(ws, 0, zero_bytes, stream);

  const int EB = (NE + 255) / 256;          // 3125
  const int NB = (NN + 255) / 256;          // 196
  const int WB = (NN * 64 + 255) / 256;     // 12500 (wave-per-node kernels)
  const int GB = (NN + 31) / 32;            // 1563 (GEMM: 32 rows/block)

  // CSR + graph counts (built once, reused for all 3 layers)
  k_count<<<EB, 256, 0, stream>>>(dst, cnt);
  k_scan<<<1, 1024, 0, stream>>>(cnt, offp, cursor);
  k_fill<<<EB, 256, 0, stream>>>(src, dst, cursor, csr);
  k_gcount<<<NB, 256, 0, stream>>>(batch, gcnt);

  // ---- layer 0 ----
  k_agg<<<WB, 256, 0, stream>>>(x, offp, csr, B1);
  k_sage_linear<<<GB, 256, 0, stream>>>(B1, x, c0_Wl, c0_bl, c0_Wr, B2);
  k_ln_stats<<<WB, 256, 0, stream>>>(B2, batch, gsum0, gsq0);
  k_ln_apply<<<WB, 256, 0, stream>>>(B2, batch, gcnt, gsum0, gsq0, ln0_w, ln0_b, p0_a, B2); // h1

  // z1 = h1 + x@s0_W
  k_skip_linear<<<GB, 256, 0, stream>>>(x, s0_W, B2, nullptr, B3);

  // ---- layer 1 ----
  k_agg<<<WB, 256, 0, stream>>>(B3, offp, csr, B1);
  k_sage_linear<<<GB, 256, 0, stream>>>(B1, B3, c1_Wl, c1_bl, c1_Wr, B4);
  k_ln_stats<<<WB, 256, 0, stream>>>(B4, batch, gsum1, gsq1);
  k_ln_apply<<<WB, 256, 0, stream>>>(B4, batch, gcnt, gsum1, gsq1, ln1_w, ln1_b, p1_a, B4); // h2

  // z2 = h1 + h2 + x@s1_W
  k_skip_linear<<<GB, 256, 0, stream>>>(x, s1_W, B2, B4, B3);

  // ---- layer 2 ----
  k_agg<<<WB, 256, 0, stream>>>(B3, offp, csr, B1);
  k_sage_linear<<<GB, 256, 0, stream>>>(B1, B3, c2_Wl, c2_bl, c2_Wr, out);
  k_ln_stats<<<WB, 256, 0, stream>>>(out, batch, gsum2, gsq2);
  k_ln_apply<<<WB, 256, 0, stream>>>(out, batch, gcnt, gsum2, gsq2, ln2_w, ln2_b, p2_a, out);
}

// Round 2
// 955.650 us; speedup vs baseline: 1.8323x; 1.8323x over previous
//
#include <hip/hip_runtime.h>

#define NN 50000
#define NE 800000
#define NG 128
#define NF 64
#define EPSV 1e-5f

// ======================= CSR build =======================
__global__ void k_count(const int* __restrict__ dst, int* __restrict__ cnt) {
  int e = blockIdx.x * 256 + threadIdx.x;
  if (e < NE) atomicAdd(&cnt[dst[e]], 1);
}

__global__ __launch_bounds__(1024) void k_scan(const int* __restrict__ cnt,
                                               int* __restrict__ off,
                                               int* __restrict__ cursor) {
  __shared__ int sh[1024];
  int tid = threadIdx.x;
  const int CH = (NN + 1023) / 1024;  // 49
  int b = tid * CH;
  int e = b + CH; if (e > NN) e = NN;
  if (b > NN) b = NN;
  int sum = 0;
  for (int i = b; i < e; ++i) sum += cnt[i];
  sh[tid] = sum;
  __syncthreads();
  for (int d = 1; d < 1024; d <<= 1) {
    int t = (tid >= d) ? sh[tid - d] : 0;
    __syncthreads();
    sh[tid] += t;
    __syncthreads();
  }
  int excl = sh[tid] - sum;
  for (int i = b; i < e; ++i) { off[i] = excl; cursor[i] = excl; excl += cnt[i]; }
  if (tid == 1023) off[NN] = sh[1023];
}

__global__ void k_fill(const int* __restrict__ src, const int* __restrict__ dst,
                       int* __restrict__ cursor, int* __restrict__ csr) {
  int e = blockIdx.x * 256 + threadIdx.x;
  if (e < NE) {
    int p = atomicAdd(&cursor[dst[e]], 1);
    csr[p] = src[e];
  }
}

__global__ void k_gcount(const int* __restrict__ batch, int* __restrict__ gcnt) {
  int i = blockIdx.x * 256 + threadIdx.x;
  if (i < NN) atomicAdd(&gcnt[batch[i]], 1);
}

// ============ mean aggregation: one wave per node, lane = feature ============
__global__ __launch_bounds__(256) void k_agg(const float* __restrict__ in,
                                             const int* __restrict__ off,
                                             const int* __restrict__ csr,
                                             float* __restrict__ out) {
  int wid = (blockIdx.x * 256 + threadIdx.x) >> 6;
  int lane = threadIdx.x & 63;
  if (wid >= NN) return;
  int s0 = off[wid], s1 = off[wid + 1];
  float acc = 0.f;
  for (int j = s0; j < s1; ++j) {
    int s = csr[j];
    acc += in[s * NF + lane];
  }
  int d = s1 - s0;
  out[wid * NF + lane] = (d > 0) ? acc / (float)d : 0.f;
}

// ============ dual GEMM + fused graph-LN stats ============
// out = A@Wl + bl + X@Wr ; also accumulates per-graph sum / sum-of-squares.
__global__ __launch_bounds__(256) void k_sage_linear(const float* __restrict__ A,
                                                     const float* __restrict__ X,
                                                     const float* __restrict__ Wl,
                                                     const float* __restrict__ bl,
                                                     const float* __restrict__ Wr,
                                                     const int* __restrict__ batch,
                                                     float* __restrict__ gsum,
                                                     float* __restrict__ gsq,
                                                     float* __restrict__ out) {
  __shared__ float sWl[64][64];
  __shared__ float sWr[64][64];
  __shared__ float gs[NG];
  __shared__ float gq[NG];
  int tid = threadIdx.x;
  for (int i = tid; i < 64 * 64; i += 256) {
    sWl[i >> 6][i & 63] = Wl[i];
    sWr[i >> 6][i & 63] = Wr[i];
  }
  if (tid < NG) { gs[tid] = 0.f; gq[tid] = 0.f; }
  __syncthreads();
  int lane = tid & 63;
  int wave = tid >> 6;
  const int RPW = 8;                       // rows per wave
  int row0 = blockIdx.x * (4 * RPW) + wave * RPW;
  float bias = bl[lane];
  for (int r = row0; r < row0 + RPW; ++r) {
    if (r >= NN) break;
    float av = A[r * NF + lane];
    float xv = X[r * NF + lane];
    float acc = bias;
#pragma unroll
    for (int k = 0; k < 64; ++k) {
      acc += __shfl(av, k) * sWl[k][lane];
      acc += __shfl(xv, k) * sWr[k][lane];
    }
    out[r * NF + lane] = acc;
    // LN stats: wave-reduce row sum / sumsq
    float s = acc, q = acc * acc;
#pragma unroll
    for (int d = 32; d > 0; d >>= 1) {
      s += __shfl_xor(s, d);
      q += __shfl_xor(q, d);
    }
    if (lane == 0) {
      int g = batch[r];
      atomicAdd(&gs[g], s);
      atomicAdd(&gq[g], q);
    }
  }
  __syncthreads();
  if (tid < NG) {
    float s = gs[tid], q = gq[tid];
    if (s != 0.f || q != 0.f) {          // untouched graphs contribute nothing
      atomicAdd(&gsum[tid], s);
      atomicAdd(&gsq[tid], q);
    }
  }
}

// ============ skip GEMM: out = add0 (+ add1) + X@W ============
__global__ __launch_bounds__(256) void k_skip_linear(const float* __restrict__ X,
                                                     const float* __restrict__ W,
                                                     const float* __restrict__ add0,
                                                     const float* __restrict__ add1,
                                                     float* __restrict__ out) {
  __shared__ float sW[64][64];
  int tid = threadIdx.x;
  for (int i = tid; i < 64 * 64; i += 256) sW[i >> 6][i & 63] = W[i];
  __syncthreads();
  int lane = tid & 63;
  int wave = tid >> 6;
  const int RPW = 8;
  int row0 = blockIdx.x * (4 * RPW) + wave * RPW;
  for (int r = row0; r < row0 + RPW; ++r) {
    if (r >= NN) break;
    float xv = X[r * NF + lane];
    float acc = add0[r * NF + lane];
    if (add1) acc += add1[r * NF + lane];
#pragma unroll
    for (int k = 0; k < 64; ++k) {
      acc += __shfl(xv, k) * sW[k][lane];
    }
    out[r * NF + lane] = acc;
  }
}

// ============ graph LayerNorm apply + affine + PReLU (in-place capable) ============
__global__ __launch_bounds__(256) void k_ln_apply(const float* __restrict__ t,
                                                  const int* __restrict__ batch,
                                                  const int* __restrict__ gcnt,
                                                  const float* __restrict__ gsum,
                                                  const float* __restrict__ gsq,
                                                  const float* __restrict__ w,
                                                  const float* __restrict__ b,
                                                  const float* __restrict__ alpha,
                                                  float* __restrict__ out) {
  int wid = (blockIdx.x * 256 + threadIdx.x) >> 6;
  int lane = threadIdx.x & 63;
  if (wid >= NN) return;
  int g = batch[wid];
  float norm = fmaxf((float)gcnt[g], 1.f) * (float)NF;
  float mean = gsum[g] / norm;
  float var = gsq[g] / norm - mean * mean;
  float rstd = rsqrtf(var + EPSV);
  float a = alpha[0];
  float v = t[wid * NF + lane];
  v = (v - mean) * rstd;
  v = v * w[lane] + b[lane];
  out[wid * NF + lane] = (v >= 0.f) ? v : a * v;
}

// ======================= launch =======================
extern "C" void kernel_launch(void* const* d_in, const int* in_sizes, int n_in,
                              void* d_out, int out_size, void* d_ws, size_t ws_size,
                              hipStream_t stream) {
  const float* x     = (const float*)d_in[0];
  const float* c0_Wl = (const float*)d_in[1];
  const float* c0_bl = (const float*)d_in[2];
  const float* c0_Wr = (const float*)d_in[3];
  const float* c1_Wl = (const float*)d_in[4];
  const float* c1_bl = (const float*)d_in[5];
  const float* c1_Wr = (const float*)d_in[6];
  const float* c2_Wl = (const float*)d_in[7];
  const float* c2_bl = (const float*)d_in[8];
  const float* c2_Wr = (const float*)d_in[9];
  const float* s0_W  = (const float*)d_in[10];
  const float* s1_W  = (const float*)d_in[11];
  const float* ln0_w = (const float*)d_in[12];
  const float* ln0_b = (const float*)d_in[13];
  const float* ln1_w = (const float*)d_in[14];
  const float* ln1_b = (const float*)d_in[15];
  const float* ln2_w = (const float*)d_in[16];
  const float* ln2_b = (const float*)d_in[17];
  const float* p0_a  = (const float*)d_in[18];
  const float* p1_a  = (const float*)d_in[19];
  const float* p2_a  = (const float*)d_in[20];
  const int*   ei    = (const int*)d_in[21];   // [2, E] int32
  const int*   batch = (const int*)d_in[22];   // [N] int32
  float* out = (float*)d_out;

  const int* src = ei;
  const int* dst = ei + NE;

  // ---- workspace layout ----
  char* ws = (char*)d_ws;
  const size_t off_cnt    = 0;                          // N ints (zeroed)
  const size_t off_gcnt   = 200192;                     // G ints (zeroed)
  const size_t off_stats  = 200704;                     // 6*G floats (zeroed)
  const size_t zero_bytes = 203776;
  const size_t off_off    = 203776;                     // N+1 ints
  const size_t off_cursor = 404224;                     // N ints
  const size_t off_csr    = 604416;                     // E ints
  const size_t off_B1     = 3804416;                    // N*F floats
  const size_t off_B2     = off_B1 + 12800000;
  const size_t off_B3     = off_B2 + 12800000;
  const size_t off_B4     = off_B3 + 12800000;

  int*   cnt    = (int*)(ws + off_cnt);
  int*   gcnt   = (int*)(ws + off_gcnt);
  float* stats  = (float*)(ws + off_stats);
  int*   offp   = (int*)(ws + off_off);
  int*   cursor = (int*)(ws + off_cursor);
  int*   csr    = (int*)(ws + off_csr);
  float* B1     = (float*)(ws + off_B1);   // aggregation output
  float* B2     = (float*)(ws + off_B2);   // h1
  float* B3     = (float*)(ws + off_B3);   // z
  float* B4     = (float*)(ws + off_B4);   // h2
  (void)ws_size; (void)in_sizes; (void)n_in; (void)out_size;

  float* gsum0 = stats + 0 * NG; float* gsq0 = stats + 1 * NG;
  float* gsum1 = stats + 2 * NG; float* gsq1 = stats + 3 * NG;
  float* gsum2 = stats + 4 * NG; float* gsq2 = stats + 5 * NG;

  hipMemsetAsync(ws, 0, zero_bytes, stream);

  const int EB = (NE + 255) / 256;          // 3125
  const int NB = (NN + 255) / 256;          // 196
  const int WB = (NN * 64 + 255) / 256;     // 12500 (wave-per-node kernels)
  const int GB = (NN + 31) / 32;            // 1563 (GEMM: 32 rows/block)

  // CSR + graph counts (built once, reused for all 3 layers)
  k_count<<<EB, 256, 0, stream>>>(dst, cnt);
  k_scan<<<1, 1024, 0, stream>>>(cnt, offp, cursor);
  k_fill<<<EB, 256, 0, stream>>>(src, dst, cursor, csr);
  k_gcount<<<NB, 256, 0, stream>>>(batch, gcnt);

  // ---- layer 0 ----
  k_agg<<<WB, 256, 0, stream>>>(x, offp, csr, B1);
  k_sage_linear<<<GB, 256, 0, stream>>>(B1, x, c0_Wl, c0_bl, c0_Wr, batch, gsum0, gsq0, B2);
  k_ln_apply<<<WB, 256, 0, stream>>>(B2, batch, gcnt, gsum0, gsq0, ln0_w, ln0_b, p0_a, B2); // h1

  // z1 = h1 + x@s0_W
  k_skip_linear<<<GB, 256, 0, stream>>>(x, s0_W, B2, nullptr, B3);

  // ---- layer 1 ----
  k_agg<<<WB, 256, 0, stream>>>(B3, offp, csr, B1);
  k_sage_linear<<<GB, 256, 0, stream>>>(B1, B3, c1_Wl, c1_bl, c1_Wr, batch, gsum1, gsq1, B4);
  k_ln_apply<<<WB, 256, 0, stream>>>(B4, batch, gcnt, gsum1, gsq1, ln1_w, ln1_b, p1_a, B4); // h2

  // z2 = h1 + h2 + x@s1_W
  k_skip_linear<<<GB, 256, 0, stream>>>(x, s1_W, B2, B4, B3);

  // ---- layer 2 ----
  k_agg<<<WB, 256, 0, stream>>>(B3, offp, csr, B1);
  k_sage_linear<<<GB, 256, 0, stream>>>(B1, B3, c2_Wl, c2_bl, c2_Wr, batch, gsum2, gsq2, out);
  k_ln_apply<<<WB, 256, 0, stream>>>(out, batch, gcnt, gsum2, gsq2, ln2_w, ln2_b, p2_a, out);
}

// Round 3
// 536.624 us; speedup vs baseline: 3.2631x; 1.7809x over previous
//
#include <hip/hip_runtime.h>

#define NN 50000
#define NE 800000
#define NG 128
#define NF 64
#define EPSV 1e-5f
#define RPW_S 16   // rows per wave in GEMM kernels

// ======================= CSR build =======================
__global__ void k_count(const int* __restrict__ dst, int* __restrict__ cnt) {
  int e = blockIdx.x * 256 + threadIdx.x;
  if (e < NE) atomicAdd(&cnt[dst[e]], 1);
}

__global__ __launch_bounds__(1024) void k_scan(const int* __restrict__ cnt,
                                               int* __restrict__ off,
                                               int* __restrict__ cursor) {
  __shared__ int sh[1024];
  int tid = threadIdx.x;
  const int CH = (NN + 1023) / 1024;  // 49
  int b = tid * CH;
  int e = b + CH; if (e > NN) e = NN;
  if (b > NN) b = NN;
  int sum = 0;
  for (int i = b; i < e; ++i) sum += cnt[i];
  sh[tid] = sum;
  __syncthreads();
  for (int d = 1; d < 1024; d <<= 1) {
    int t = (tid >= d) ? sh[tid - d] : 0;
    __syncthreads();
    sh[tid] += t;
    __syncthreads();
  }
  int excl = sh[tid] - sum;
  for (int i = b; i < e; ++i) { off[i] = excl; cursor[i] = excl; excl += cnt[i]; }
  if (tid == 1023) off[NN] = sh[1023];
}

__global__ void k_fill(const int* __restrict__ src, const int* __restrict__ dst,
                       int* __restrict__ cursor, int* __restrict__ csr) {
  int e = blockIdx.x * 256 + threadIdx.x;
  if (e < NE) {
    int p = atomicAdd(&cursor[dst[e]], 1);
    csr[p] = src[e];
  }
}

// graph boundaries from sorted batch: bound[g] = first index i with batch[i] >= g
__global__ void k_bounds(const int* __restrict__ batch, int* __restrict__ bound) {
  int i = blockIdx.x * 256 + threadIdx.x;
  if (i >= NN) return;
  int b1 = batch[i];
  int b0 = (i == 0) ? -1 : batch[i - 1];
  for (int g = b0 + 1; g <= b1; ++g) bound[g] = i;
  if (i == NN - 1) {
    for (int g = b1 + 1; g <= NG; ++g) bound[g] = NN;
  }
}

// ============ mean aggregation: 16 lanes x float4 per node (4 nodes/wave) ============
__global__ __launch_bounds__(256) void k_agg(const float* __restrict__ in,
                                             const int* __restrict__ off,
                                             const int* __restrict__ csr,
                                             float* __restrict__ out) {
  int t = blockIdx.x * 256 + threadIdx.x;
  int node = t >> 4;
  int fl = (t & 15) << 2;
  if (node >= NN) return;
  int s0 = off[node], s1 = off[node + 1];
  float4 acc = make_float4(0.f, 0.f, 0.f, 0.f);
  for (int j = s0; j < s1; ++j) {
    int s = csr[j];
    float4 v = *(const float4*)&in[s * NF + fl];
    acc.x += v.x; acc.y += v.y; acc.z += v.z; acc.w += v.w;
  }
  float inv = (s1 > s0) ? 1.f / (float)(s1 - s0) : 0.f;
  *(float4*)&out[node * NF + fl] =
      make_float4(acc.x * inv, acc.y * inv, acc.z * inv, acc.w * inv);
}

// ============ dual GEMM (register weights, uniform s_load rows) + fused LN stats ============
// out = A@Wl + bl + X@Wr ; per-graph sum/sumsq accumulated (deferred flush per graph-run)
__global__ __launch_bounds__(256, 3) void k_sage_linear(const float* __restrict__ A,
                                                        const float* __restrict__ X,
                                                        const float* __restrict__ Wl,
                                                        const float* __restrict__ bl,
                                                        const float* __restrict__ Wr,
                                                        const int* __restrict__ batch,
                                                        float* __restrict__ gsum,
                                                        float* __restrict__ gsq,
                                                        float* __restrict__ out) {
  __shared__ float gs[NG];
  __shared__ float gq[NG];
  int tid = threadIdx.x;
  if (tid < NG) { gs[tid] = 0.f; gq[tid] = 0.f; }
  __syncthreads();
  int lane = tid & 63;
  int wave = __builtin_amdgcn_readfirstlane(tid >> 6);
  // weight columns into registers (static unrolled indices -> VGPRs)
  float wl[64], wr[64];
#pragma unroll
  for (int k = 0; k < 64; ++k) {
    wl[k] = Wl[k * NF + lane];
    wr[k] = Wr[k * NF + lane];
  }
  float bias = bl[lane];
  int row0 = blockIdx.x * (4 * RPW_S) + wave * RPW_S;
  int gcur = -1;
  float ps = 0.f, pq = 0.f;
  for (int rr = 0; rr < RPW_S; ++rr) {
    int r = row0 + rr;
    if (r >= NN) break;
    const float* Ar = A + (size_t)r * NF;
    const float* Xr = X + (size_t)r * NF;
    float acc0 = bias, acc1 = 0.f, acc2 = 0.f, acc3 = 0.f;
#pragma unroll
    for (int k = 0; k < 64; k += 4) {
      acc0 += Ar[k]     * wl[k];
      acc1 += Ar[k + 1] * wl[k + 1];
      acc2 += Ar[k + 2] * wl[k + 2];
      acc3 += Ar[k + 3] * wl[k + 3];
      acc0 += Xr[k]     * wr[k];
      acc1 += Xr[k + 1] * wr[k + 1];
      acc2 += Xr[k + 2] * wr[k + 2];
      acc3 += Xr[k + 3] * wr[k + 3];
    }
    float acc = (acc0 + acc1) + (acc2 + acc3);
    out[(size_t)r * NF + lane] = acc;
    int g = batch[r];                       // uniform
    if (g != gcur) {
      if (gcur >= 0) {
        float s = ps, q = pq;
#pragma unroll
        for (int d = 32; d > 0; d >>= 1) { s += __shfl_xor(s, d); q += __shfl_xor(q, d); }
        if (lane == 0) { atomicAdd(&gs[gcur], s); atomicAdd(&gq[gcur], q); }
      }
      gcur = g; ps = 0.f; pq = 0.f;
    }
    ps += acc; pq += acc * acc;
  }
  if (gcur >= 0) {
    float s = ps, q = pq;
#pragma unroll
    for (int d = 32; d > 0; d >>= 1) { s += __shfl_xor(s, d); q += __shfl_xor(q, d); }
    if (lane == 0) { atomicAdd(&gs[gcur], s); atomicAdd(&gq[gcur], q); }
  }
  __syncthreads();
  if (tid < NG) {
    float s = gs[tid], q = gq[tid];
    if (s != 0.f || q != 0.f) { atomicAdd(&gsum[tid], s); atomicAdd(&gsq[tid], q); }
  }
}

// ============ skip GEMM with folded LN+PReLU on the residual inputs ============
// out = LN0(t0) [+ LN1(t1)] + X@W
__global__ __launch_bounds__(256, 4) void k_skip_linear(
    const float* __restrict__ X, const float* __restrict__ W,
    const float* __restrict__ t0, const float* __restrict__ gsum0, const float* __restrict__ gsq0,
    const float* __restrict__ lw0, const float* __restrict__ lb0, const float* __restrict__ pa0,
    const float* __restrict__ t1, const float* __restrict__ gsum1, const float* __restrict__ gsq1,
    const float* __restrict__ lw1, const float* __restrict__ lb1, const float* __restrict__ pa1,
    const int* __restrict__ batch, const int* __restrict__ bound,
    float* __restrict__ out) {
  int tid = threadIdx.x;
  int lane = tid & 63;
  int wave = __builtin_amdgcn_readfirstlane(tid >> 6);
  float w[64];
#pragma unroll
  for (int k = 0; k < 64; ++k) w[k] = W[k * NF + lane];
  float w0l = lw0[lane], b0l = lb0[lane], a0 = pa0[0];
  float w1l = 0.f, b1l = 0.f, a1 = 0.f;
  if (t1) { w1l = lw1[lane]; b1l = lb1[lane]; a1 = pa1[0]; }
  int row0 = blockIdx.x * (4 * RPW_S) + wave * RPW_S;
  for (int rr = 0; rr < RPW_S; ++rr) {
    int r = row0 + rr;
    if (r >= NN) break;
    int g = batch[r];
    float cnt = (float)(bound[g + 1] - bound[g]);
    float norm = fmaxf(cnt, 1.f) * (float)NF;
    float m0 = gsum0[g] / norm;
    float v0 = gsq0[g] / norm - m0 * m0;
    float rs0 = rsqrtf(v0 + EPSV);
    float u = t0[(size_t)r * NF + lane];
    u = (u - m0) * rs0 * w0l + b0l;
    float acc0 = (u >= 0.f) ? u : a0 * u;
    float acc1 = 0.f, acc2 = 0.f, acc3 = 0.f;
    if (t1) {
      float m1 = gsum1[g] / norm;
      float v1 = gsq1[g] / norm - m1 * m1;
      float rs1 = rsqrtf(v1 + EPSV);
      float u1 = t1[(size_t)r * NF + lane];
      u1 = (u1 - m1) * rs1 * w1l + b1l;
      acc1 = (u1 >= 0.f) ? u1 : a1 * u1;
    }
    const float* Xr = X + (size_t)r * NF;
#pragma unroll
    for (int k = 0; k < 64; k += 4) {
      acc0 += Xr[k]     * w[k];
      acc1 += Xr[k + 1] * w[k + 1];
      acc2 += Xr[k + 2] * w[k + 2];
      acc3 += Xr[k + 3] * w[k + 3];
    }
    out[(size_t)r * NF + lane] = (acc0 + acc1) + (acc2 + acc3);
  }
}

// ============ graph LayerNorm apply + affine + PReLU (final layer) ============
__global__ __launch_bounds__(256) void k_ln_apply(const float* __restrict__ t,
                                                  const int* __restrict__ batch,
                                                  const int* __restrict__ bound,
                                                  const float* __restrict__ gsum,
                                                  const float* __restrict__ gsq,
                                                  const float* __restrict__ w,
                                                  const float* __restrict__ b,
                                                  const float* __restrict__ alpha,
                                                  float* __restrict__ out) {
  int wid = (blockIdx.x * 256 + threadIdx.x) >> 6;
  int lane = threadIdx.x & 63;
  if (wid >= NN) return;
  int g = batch[wid];
  float cnt = (float)(bound[g + 1] - bound[g]);
  float norm = fmaxf(cnt, 1.f) * (float)NF;
  float mean = gsum[g] / norm;
  float var = gsq[g] / norm - mean * mean;
  float rstd = rsqrtf(var + EPSV);
  float a = alpha[0];
  float v = t[wid * NF + lane];
  v = (v - mean) * rstd;
  v = v * w[lane] + b[lane];
  out[wid * NF + lane] = (v >= 0.f) ? v : a * v;
}

// ======================= launch =======================
extern "C" void kernel_launch(void* const* d_in, const int* in_sizes, int n_in,
                              void* d_out, int out_size, void* d_ws, size_t ws_size,
                              hipStream_t stream) {
  const float* x     = (const float*)d_in[0];
  const float* c0_Wl = (const float*)d_in[1];
  const float* c0_bl = (const float*)d_in[2];
  const float* c0_Wr = (const float*)d_in[3];
  const float* c1_Wl = (const float*)d_in[4];
  const float* c1_bl = (const float*)d_in[5];
  const float* c1_Wr = (const float*)d_in[6];
  const float* c2_Wl = (const float*)d_in[7];
  const float* c2_bl = (const float*)d_in[8];
  const float* c2_Wr = (const float*)d_in[9];
  const float* s0_W  = (const float*)d_in[10];
  const float* s1_W  = (const float*)d_in[11];
  const float* ln0_w = (const float*)d_in[12];
  const float* ln0_b = (const float*)d_in[13];
  const float* ln1_w = (const float*)d_in[14];
  const float* ln1_b = (const float*)d_in[15];
  const float* ln2_w = (const float*)d_in[16];
  const float* ln2_b = (const float*)d_in[17];
  const float* p0_a  = (const float*)d_in[18];
  const float* p1_a  = (const float*)d_in[19];
  const float* p2_a  = (const float*)d_in[20];
  const int*   ei    = (const int*)d_in[21];   // [2, E] int32
  const int*   batch = (const int*)d_in[22];   // [N] int32
  float* out = (float*)d_out;

  const int* src = ei;
  const int* dst = ei + NE;

  // ---- workspace layout ----
  char* ws = (char*)d_ws;
  const size_t off_cnt    = 0;                          // N ints (zeroed)
  const size_t off_stats  = 200704;                     // 6*G floats (zeroed)
  const size_t zero_bytes = 204800;
  const size_t off_bound  = 204800;                     // G+1 ints
  const size_t off_off    = 205824;                     // N+1 ints
  const size_t off_cursor = 406272;                     // N ints
  const size_t off_csr    = 606464;                     // E ints
  const size_t off_B1     = 3806464;                    // N*F floats
  const size_t off_B2     = off_B1 + 12800000;
  const size_t off_B3     = off_B2 + 12800000;
  const size_t off_B4     = off_B3 + 12800000;

  int*   cnt    = (int*)(ws + off_cnt);
  float* stats  = (float*)(ws + off_stats);
  int*   bound  = (int*)(ws + off_bound);
  int*   offp   = (int*)(ws + off_off);
  int*   cursor = (int*)(ws + off_cursor);
  int*   csr    = (int*)(ws + off_csr);
  float* B1     = (float*)(ws + off_B1);   // aggregation output
  float* B2     = (float*)(ws + off_B2);   // h1 (raw pre-LN)
  float* B3     = (float*)(ws + off_B3);   // z
  float* B4     = (float*)(ws + off_B4);   // h2 (raw pre-LN)
  (void)ws_size; (void)in_sizes; (void)n_in; (void)out_size;

  float* gsum0 = stats + 0 * NG; float* gsq0 = stats + 1 * NG;
  float* gsum1 = stats + 2 * NG; float* gsq1 = stats + 3 * NG;
  float* gsum2 = stats + 4 * NG; float* gsq2 = stats + 5 * NG;

  hipMemsetAsync(ws, 0, zero_bytes, stream);

  const int EB  = (NE + 255) / 256;            // 3125
  const int NB  = (NN + 255) / 256;            // 196
  const int WB  = (NN * 64 + 255) / 256;       // 12500 (wave-per-node)
  const int AB  = (NN * 16 + 255) / 256;       // 3125  (agg: 16 lanes/node)
  const int GB2 = (NN + 4 * RPW_S - 1) / (4 * RPW_S);  // 782 (GEMM: 64 rows/block)

  // CSR + graph bounds (built once, reused for all 3 layers)
  k_count<<<EB, 256, 0, stream>>>(dst, cnt);
  k_scan<<<1, 1024, 0, stream>>>(cnt, offp, cursor);
  k_fill<<<EB, 256, 0, stream>>>(src, dst, cursor, csr);
  k_bounds<<<NB, 256, 0, stream>>>(batch, bound);

  // ---- layer 0 ----
  k_agg<<<AB, 256, 0, stream>>>(x, offp, csr, B1);
  k_sage_linear<<<GB2, 256, 0, stream>>>(B1, x, c0_Wl, c0_bl, c0_Wr, batch, gsum0, gsq0, B2);
  // z1 = LN0(B2) + x@s0_W
  k_skip_linear<<<GB2, 256, 0, stream>>>(x, s0_W,
                                         B2, gsum0, gsq0, ln0_w, ln0_b, p0_a,
                                         nullptr, nullptr, nullptr, nullptr, nullptr, nullptr,
                                         batch, bound, B3);

  // ---- layer 1 ----
  k_agg<<<AB, 256, 0, stream>>>(B3, offp, csr, B1);
  k_sage_linear<<<GB2, 256, 0, stream>>>(B1, B3, c1_Wl, c1_bl, c1_Wr, batch, gsum1, gsq1, B4);
  // z2 = LN0(B2) + LN1(B4) + x@s1_W
  k_skip_linear<<<GB2, 256, 0, stream>>>(x, s1_W,
                                         B2, gsum0, gsq0, ln0_w, ln0_b, p0_a,
                                         B4, gsum1, gsq1, ln1_w, ln1_b, p1_a,
                                         batch, bound, B3);

  // ---- layer 2 ----
  k_agg<<<AB, 256, 0, stream>>>(B3, offp, csr, B1);
  k_sage_linear<<<GB2, 256, 0, stream>>>(B1, B3, c2_Wl, c2_bl, c2_Wr, batch, gsum2, gsq2, out);
  k_ln_apply<<<WB, 256, 0, stream>>>(out, batch, bound, gsum2, gsq2, ln2_w, ln2_b, p2_a, out);
}

// Round 4
// 437.183 us; speedup vs baseline: 4.0053x; 1.2275x over previous
//
#include <hip/hip_runtime.h>

#define NN 50000
#define NE 800000
#define NG 128
#define NF 64
#define EPSV 1e-5f
#define RPW_S 16   // rows per wave in GEMM kernels
#define SCB 196    // scan blocks = ceil(NN/256)

// ======================= CSR build =======================
__global__ void k_count(const int* __restrict__ dst, int* __restrict__ cnt) {
  int e = blockIdx.x * 256 + threadIdx.x;
  if (e < NE) atomicAdd(&cnt[dst[e]], 1);
}

// ---- 3-phase multi-block exclusive scan of cnt[NN] -> off/cursor ----
__global__ __launch_bounds__(256) void k_scan1(const int* __restrict__ cnt,
                                               int* __restrict__ off,
                                               int* __restrict__ part) {
  __shared__ int sh[256];
  int tid = threadIdx.x;
  int i = blockIdx.x * 256 + tid;
  int v = (i < NN) ? cnt[i] : 0;
  sh[tid] = v;
  __syncthreads();
  for (int d = 1; d < 256; d <<= 1) {
    int t = (tid >= d) ? sh[tid - d] : 0;
    __syncthreads();
    sh[tid] += t;
    __syncthreads();
  }
  if (i < NN) off[i] = sh[tid] - v;          // local exclusive
  if (tid == 255) part[blockIdx.x] = sh[255]; // block total
}

__global__ __launch_bounds__(256) void k_scan2(int* __restrict__ part,
                                               int* __restrict__ off) {
  __shared__ int sh[256];
  int tid = threadIdx.x;
  int v = (tid < SCB) ? part[tid] : 0;
  sh[tid] = v;
  __syncthreads();
  for (int d = 1; d < 256; d <<= 1) {
    int t = (tid >= d) ? sh[tid - d] : 0;
    __syncthreads();
    sh[tid] += t;
    __syncthreads();
  }
  if (tid < SCB) part[tid] = sh[tid] - v;     // exclusive block prefix
  if (tid == 255) off[NN] = sh[255];          // grand total (= NE)
}

__global__ __launch_bounds__(256) void k_scan3(int* __restrict__ off,
                                               int* __restrict__ cursor,
                                               const int* __restrict__ part) {
  int i = blockIdx.x * 256 + threadIdx.x;
  if (i < NN) {
    int v = off[i] + part[blockIdx.x];
    off[i] = v;
    cursor[i] = v;
  }
}

__global__ void k_fill(const int* __restrict__ src, const int* __restrict__ dst,
                       int* __restrict__ cursor, int* __restrict__ csr) {
  int e = blockIdx.x * 256 + threadIdx.x;
  if (e < NE) {
    int p = atomicAdd(&cursor[dst[e]], 1);
    csr[p] = src[e];
  }
}

// graph boundaries from sorted batch: bound[g] = first index i with batch[i] >= g
__global__ void k_bounds(const int* __restrict__ batch, int* __restrict__ bound) {
  int i = blockIdx.x * 256 + threadIdx.x;
  if (i >= NN) return;
  int b1 = batch[i];
  int b0 = (i == 0) ? -1 : batch[i - 1];
  for (int g = b0 + 1; g <= b1; ++g) bound[g] = i;
  if (i == NN - 1) {
    for (int g = b1 + 1; g <= NG; ++g) bound[g] = NN;
  }
}

// ============ mean aggregation: 16 lanes x float4 per node (4 nodes/wave) ============
__global__ __launch_bounds__(256) void k_agg(const float* __restrict__ in,
                                             const int* __restrict__ off,
                                             const int* __restrict__ csr,
                                             float* __restrict__ out) {
  int t = blockIdx.x * 256 + threadIdx.x;
  int node = t >> 4;
  int fl = (t & 15) << 2;
  if (node >= NN) return;
  int s0 = off[node], s1 = off[node + 1];
  float4 acc = make_float4(0.f, 0.f, 0.f, 0.f);
  for (int j = s0; j < s1; ++j) {
    int s = csr[j];
    float4 v = *(const float4*)&in[s * NF + fl];
    acc.x += v.x; acc.y += v.y; acc.z += v.z; acc.w += v.w;
  }
  float inv = (s1 > s0) ? 1.f / (float)(s1 - s0) : 0.f;
  *(float4*)&out[node * NF + fl] =
      make_float4(acc.x * inv, acc.y * inv, acc.z * inv, acc.w * inv);
}

// ============ dual GEMM (register weights, uniform s_load rows) + fused LN stats ============
__global__ __launch_bounds__(256, 3) void k_sage_linear(const float* __restrict__ A,
                                                        const float* __restrict__ X,
                                                        const float* __restrict__ Wl,
                                                        const float* __restrict__ bl,
                                                        const float* __restrict__ Wr,
                                                        const int* __restrict__ batch,
                                                        float* __restrict__ gsum,
                                                        float* __restrict__ gsq,
                                                        float* __restrict__ out) {
  __shared__ float gs[NG];
  __shared__ float gq[NG];
  int tid = threadIdx.x;
  if (tid < NG) { gs[tid] = 0.f; gq[tid] = 0.f; }
  __syncthreads();
  int lane = tid & 63;
  int wave = __builtin_amdgcn_readfirstlane(tid >> 6);
  float wl[64], wr[64];
#pragma unroll
  for (int k = 0; k < 64; ++k) {
    wl[k] = Wl[k * NF + lane];
    wr[k] = Wr[k * NF + lane];
  }
  float bias = bl[lane];
  int row0 = blockIdx.x * (4 * RPW_S) + wave * RPW_S;
  int gcur = -1;
  float ps = 0.f, pq = 0.f;
  for (int rr = 0; rr < RPW_S; ++rr) {
    int r = row0 + rr;
    if (r >= NN) break;
    const float* Ar = A + (size_t)r * NF;
    const float* Xr = X + (size_t)r * NF;
    float acc0 = bias, acc1 = 0.f, acc2 = 0.f, acc3 = 0.f;
#pragma unroll
    for (int k = 0; k < 64; k += 4) {
      acc0 += Ar[k]     * wl[k];
      acc1 += Ar[k + 1] * wl[k + 1];
      acc2 += Ar[k + 2] * wl[k + 2];
      acc3 += Ar[k + 3] * wl[k + 3];
      acc0 += Xr[k]     * wr[k];
      acc1 += Xr[k + 1] * wr[k + 1];
      acc2 += Xr[k + 2] * wr[k + 2];
      acc3 += Xr[k + 3] * wr[k + 3];
    }
    float acc = (acc0 + acc1) + (acc2 + acc3);
    out[(size_t)r * NF + lane] = acc;
    int g = batch[r];                       // uniform
    if (g != gcur) {
      if (gcur >= 0) {
        float s = ps, q = pq;
#pragma unroll
        for (int d = 32; d > 0; d >>= 1) { s += __shfl_xor(s, d); q += __shfl_xor(q, d); }
        if (lane == 0) { atomicAdd(&gs[gcur], s); atomicAdd(&gq[gcur], q); }
      }
      gcur = g; ps = 0.f; pq = 0.f;
    }
    ps += acc; pq += acc * acc;
  }
  if (gcur >= 0) {
    float s = ps, q = pq;
#pragma unroll
    for (int d = 32; d > 0; d >>= 1) { s += __shfl_xor(s, d); q += __shfl_xor(q, d); }
    if (lane == 0) { atomicAdd(&gs[gcur], s); atomicAdd(&gq[gcur], q); }
  }
  __syncthreads();
  if (tid < NG) {
    float s = gs[tid], q = gq[tid];
    if (s != 0.f || q != 0.f) { atomicAdd(&gsum[tid], s); atomicAdd(&gsq[tid], q); }
  }
}

// ============ skip GEMM with folded LN+PReLU on the residual inputs ============
__global__ __launch_bounds__(256, 4) void k_skip_linear(
    const float* __restrict__ X, const float* __restrict__ W,
    const float* __restrict__ t0, const float* __restrict__ gsum0, const float* __restrict__ gsq0,
    const float* __restrict__ lw0, const float* __restrict__ lb0, const float* __restrict__ pa0,
    const float* __restrict__ t1, const float* __restrict__ gsum1, const float* __restrict__ gsq1,
    const float* __restrict__ lw1, const float* __restrict__ lb1, const float* __restrict__ pa1,
    const int* __restrict__ batch, const int* __restrict__ bound,
    float* __restrict__ out) {
  int tid = threadIdx.x;
  int lane = tid & 63;
  int wave = __builtin_amdgcn_readfirstlane(tid >> 6);
  float w[64];
#pragma unroll
  for (int k = 0; k < 64; ++k) w[k] = W[k * NF + lane];
  float w0l = lw0[lane], b0l = lb0[lane], a0 = pa0[0];
  float w1l = 0.f, b1l = 0.f, a1 = 0.f;
  if (t1) { w1l = lw1[lane]; b1l = lb1[lane]; a1 = pa1[0]; }
  int row0 = blockIdx.x * (4 * RPW_S) + wave * RPW_S;
  for (int rr = 0; rr < RPW_S; ++rr) {
    int r = row0 + rr;
    if (r >= NN) break;
    int g = batch[r];
    float cnt = (float)(bound[g + 1] - bound[g]);
    float norm = fmaxf(cnt, 1.f) * (float)NF;
    float m0 = gsum0[g] / norm;
    float v0 = gsq0[g] / norm - m0 * m0;
    float rs0 = rsqrtf(v0 + EPSV);
    float u = t0[(size_t)r * NF + lane];
    u = (u - m0) * rs0 * w0l + b0l;
    float acc0 = (u >= 0.f) ? u : a0 * u;
    float acc1 = 0.f, acc2 = 0.f, acc3 = 0.f;
    if (t1) {
      float m1 = gsum1[g] / norm;
      float v1 = gsq1[g] / norm - m1 * m1;
      float rs1 = rsqrtf(v1 + EPSV);
      float u1 = t1[(size_t)r * NF + lane];
      u1 = (u1 - m1) * rs1 * w1l + b1l;
      acc1 = (u1 >= 0.f) ? u1 : a1 * u1;
    }
    const float* Xr = X + (size_t)r * NF;
#pragma unroll
    for (int k = 0; k < 64; k += 4) {
      acc0 += Xr[k]     * w[k];
      acc1 += Xr[k + 1] * w[k + 1];
      acc2 += Xr[k + 2] * w[k + 2];
      acc3 += Xr[k + 3] * w[k + 3];
    }
    out[(size_t)r * NF + lane] = (acc0 + acc1) + (acc2 + acc3);
  }
}

// ============ graph LayerNorm apply + affine + PReLU (final layer) ============
__global__ __launch_bounds__(256) void k_ln_apply(const float* __restrict__ t,
                                                  const int* __restrict__ batch,
                                                  const int* __restrict__ bound,
                                                  const float* __restrict__ gsum,
                                                  const float* __restrict__ gsq,
                                                  const float* __restrict__ w,
                                                  const float* __restrict__ b,
                                                  const float* __restrict__ alpha,
                                                  float* __restrict__ out) {
  int wid = (blockIdx.x * 256 + threadIdx.x) >> 6;
  int lane = threadIdx.x & 63;
  if (wid >= NN) return;
  int g = batch[wid];
  float cnt = (float)(bound[g + 1] - bound[g]);
  float norm = fmaxf(cnt, 1.f) * (float)NF;
  float mean = gsum[g] / norm;
  float var = gsq[g] / norm - mean * mean;
  float rstd = rsqrtf(var + EPSV);
  float a = alpha[0];
  float v = t[wid * NF + lane];
  v = (v - mean) * rstd;
  v = v * w[lane] + b[lane];
  out[wid * NF + lane] = (v >= 0.f) ? v : a * v;
}

// ======================= launch =======================
extern "C" void kernel_launch(void* const* d_in, const int* in_sizes, int n_in,
                              void* d_out, int out_size, void* d_ws, size_t ws_size,
                              hipStream_t stream) {
  const float* x     = (const float*)d_in[0];
  const float* c0_Wl = (const float*)d_in[1];
  const float* c0_bl = (const float*)d_in[2];
  const float* c0_Wr = (const float*)d_in[3];
  const float* c1_Wl = (const float*)d_in[4];
  const float* c1_bl = (const float*)d_in[5];
  const float* c1_Wr = (const float*)d_in[6];
  const float* c2_Wl = (const float*)d_in[7];
  const float* c2_bl = (const float*)d_in[8];
  const float* c2_Wr = (const float*)d_in[9];
  const float* s0_W  = (const float*)d_in[10];
  const float* s1_W  = (const float*)d_in[11];
  const float* ln0_w = (const float*)d_in[12];
  const float* ln0_b = (const float*)d_in[13];
  const float* ln1_w = (const float*)d_in[14];
  const float* ln1_b = (const float*)d_in[15];
  const float* ln2_w = (const float*)d_in[16];
  const float* ln2_b = (const float*)d_in[17];
  const float* p0_a  = (const float*)d_in[18];
  const float* p1_a  = (const float*)d_in[19];
  const float* p2_a  = (const float*)d_in[20];
  const int*   ei    = (const int*)d_in[21];   // [2, E] int32
  const int*   batch = (const int*)d_in[22];   // [N] int32
  float* out = (float*)d_out;

  const int* src = ei;
  const int* dst = ei + NE;

  // ---- workspace layout ----
  char* ws = (char*)d_ws;
  const size_t off_cnt    = 0;                          // N ints (zeroed)
  const size_t off_stats  = 200704;                     // 6*G floats (zeroed)
  const size_t zero_bytes = 204800;
  const size_t off_bound  = 204800;                     // G+1 ints
  const size_t off_off    = 205824;                     // N+1 ints
  const size_t off_cursor = 406272;                     // N ints
  const size_t off_part   = 606464;                     // 256 ints
  const size_t off_csr    = 607744;                     // E ints
  const size_t off_B1     = 3807744;                    // N*F floats
  const size_t off_B2     = off_B1 + 12800000;
  const size_t off_B3     = off_B2 + 12800000;
  const size_t off_B4     = off_B3 + 12800000;

  int*   cnt    = (int*)(ws + off_cnt);
  float* stats  = (float*)(ws + off_stats);
  int*   bound  = (int*)(ws + off_bound);
  int*   offp   = (int*)(ws + off_off);
  int*   cursor = (int*)(ws + off_cursor);
  int*   part   = (int*)(ws + off_part);
  int*   csr    = (int*)(ws + off_csr);
  float* B1     = (float*)(ws + off_B1);   // aggregation output
  float* B2     = (float*)(ws + off_B2);   // h1 (raw pre-LN)
  float* B3     = (float*)(ws + off_B3);   // z
  float* B4     = (float*)(ws + off_B4);   // h2 (raw pre-LN)
  (void)ws_size; (void)in_sizes; (void)n_in; (void)out_size;

  float* gsum0 = stats + 0 * NG; float* gsq0 = stats + 1 * NG;
  float* gsum1 = stats + 2 * NG; float* gsq1 = stats + 3 * NG;
  float* gsum2 = stats + 4 * NG; float* gsq2 = stats + 5 * NG;

  hipMemsetAsync(ws, 0, zero_bytes, stream);

  const int EB  = (NE + 255) / 256;            // 3125
  const int NB  = (NN + 255) / 256;            // 196
  const int WB  = (NN * 64 + 255) / 256;       // 12500 (wave-per-node)
  const int AB  = (NN * 16 + 255) / 256;       // 3125  (agg: 16 lanes/node)
  const int GB2 = (NN + 4 * RPW_S - 1) / (4 * RPW_S);  // 782 (GEMM: 64 rows/block)

  // CSR + graph bounds (built once, reused for all 3 layers)
  k_count<<<EB, 256, 0, stream>>>(dst, cnt);
  k_scan1<<<SCB, 256, 0, stream>>>(cnt, offp, part);
  k_scan2<<<1, 256, 0, stream>>>(part, offp);
  k_scan3<<<SCB, 256, 0, stream>>>(offp, cursor, part);
  k_fill<<<EB, 256, 0, stream>>>(src, dst, cursor, csr);
  k_bounds<<<NB, 256, 0, stream>>>(batch, bound);

  // ---- layer 0 ----
  k_agg<<<AB, 256, 0, stream>>>(x, offp, csr, B1);
  k_sage_linear<<<GB2, 256, 0, stream>>>(B1, x, c0_Wl, c0_bl, c0_Wr, batch, gsum0, gsq0, B2);
  // z1 = LN0(B2) + x@s0_W
  k_skip_linear<<<GB2, 256, 0, stream>>>(x, s0_W,
                                         B2, gsum0, gsq0, ln0_w, ln0_b, p0_a,
                                         nullptr, nullptr, nullptr, nullptr, nullptr, nullptr,
                                         batch, bound, B3);

  // ---- layer 1 ----
  k_agg<<<AB, 256, 0, stream>>>(B3, offp, csr, B1);
  k_sage_linear<<<GB2, 256, 0, stream>>>(B1, B3, c1_Wl, c1_bl, c1_Wr, batch, gsum1, gsq1, B4);
  // z2 = LN0(B2) + LN1(B4) + x@s1_W
  k_skip_linear<<<GB2, 256, 0, stream>>>(x, s1_W,
                                         B2, gsum0, gsq0, ln0_w, ln0_b, p0_a,
                                         B4, gsum1, gsq1, ln1_w, ln1_b, p1_a,
                                         batch, bound, B3);

  // ---- layer 2 ----
  k_agg<<<AB, 256, 0, stream>>>(B3, offp, csr, B1);
  k_sage_linear<<<GB2, 256, 0, stream>>>(B1, B3, c2_Wl, c2_bl, c2_Wr, batch, gsum2, gsq2, out);
  k_ln_apply<<<WB, 256, 0, stream>>>(out, batch, bound, gsum2, gsq2, ln2_w, ln2_b, p2_a, out);
}